// Round 4
// baseline (609.592 us; speedup 1.0000x reference)
//
#include <hip/hip_runtime.h>
#include <hip/hip_bf16.h>
#include <stdint.h>

typedef __hip_bfloat16 bf16;
typedef __attribute__((ext_vector_type(8))) __bf16 bf16x8;
typedef __attribute__((ext_vector_type(8))) unsigned short ushort8;
typedef __attribute__((ext_vector_type(4))) float floatx4;

#define MFMA_16x16x32(a, b, c) __builtin_amdgcn_mfma_f32_16x16x32_bf16((a), (b), (c), 0, 0, 0)

// async global->LDS, 16B per lane. LDS dest = wave-uniform base + lane*16.
__device__ __forceinline__ void async_load16(const bf16* g, bf16* l) {
  __builtin_amdgcn_global_load_lds(
      (const __attribute__((address_space(1))) unsigned int*)g,
      (__attribute__((address_space(3))) unsigned int*)l,
      16, 0, 0);
}

// DPP cross-lane (VALU pipe, not LDS): 16-lane row reductions
template <int CTRL>
__device__ __forceinline__ float dpp_f(float x) {
  return __builtin_bit_cast(float, __builtin_amdgcn_update_dpp(
      0, __builtin_bit_cast(int, x), CTRL, 0xf, 0xf, true));
}
__device__ __forceinline__ float row_max16(float x) {
  x = fmaxf(x, dpp_f<0xB1>(x));   // quad_perm(1,0,3,2)
  x = fmaxf(x, dpp_f<0x4E>(x));   // quad_perm(2,3,0,1)
  x = fmaxf(x, dpp_f<0x124>(x));  // row_ror:4
  x = fmaxf(x, dpp_f<0x128>(x));  // row_ror:8
  return x;
}
__device__ __forceinline__ float row_sum16(float x) {
  x += dpp_f<0xB1>(x);
  x += dpp_f<0x4E>(x);
  x += dpp_f<0x124>(x);
  x += dpp_f<0x128>(x);
  return x;
}

// ---------------------------------------------------------------------------
// fp32 -> bf16 cast, 8 elems/thread
// ---------------------------------------------------------------------------
__global__ __launch_bounds__(256)
void f32_to_bf16_k(const float* __restrict__ in, bf16* __restrict__ out, int n)
{
  const int i = (blockIdx.x * 256 + threadIdx.x) * 8;
  if (i >= n) return;
  bf16 tmp[8];
#pragma unroll
  for (int j = 0; j < 8; ++j) tmp[j] = __float2bfloat16(in[i + j]);
  *(ushort8*)&out[i] = *(const ushort8*)tmp;
}

// ---------------------------------------------------------------------------
// C[M,N] = A[M,K] @ B[N,K]^T — 256x256 tile, BK=64, software-pipelined
// 4-section schedule: section q = { MFMA(quadrant q)  ||  ds_read(quadrant
// q+1) } so the LDS drain hides under the MFMA cluster (R3 serialized them:
// MfmaUtil 43.6% == MFMA/(MFMA+LDS) exactly).
// Reads (one section ahead of use): s0: bf0+bf1(t)  s1: af1(t)
//   s2: af0(t+1)  s3: none.   8/8/8/0 ds_read_b128 per section.
// Stages roll into the CURRENT buffer right after last read of each region:
//   s0: A0(t+2)  s2: B0(t+2)  s3: A1(t+2)+B1(t+2).
// W-A-R safety: stage target's last ds_read is >=2 sections old; the reading
// wave's compiler lgkmcnt before its MFMA + the section barrier certify
// completion before any wave can issue the overwriting stage.
// Waits: vmcnt(8) at s0 entry (covers bf0/bf1/af1 data) and s2 entry (covers
// af0(t+1)); 4-5 stage-sets stay in flight, stage->wait distance 5-6 sections.
// One s_barrier per section (4/K-tile).
// ---------------------------------------------------------------------------
#define G_BAR __builtin_amdgcn_s_barrier()

#define ST_A(buf, tt, h)                                                        \
  do {                                                                          \
    async_load16(pA + (size_t)((h) * 64) * K + (size_t)(tt) * 64,               \
                 &sA[buf][(h) * 4096 + lws]);                                   \
    async_load16(pA + (size_t)((h) * 64 + 128) * K + (size_t)(tt) * 64,         \
                 &sA[buf][(h) * 4096 + 8192 + lws]);                            \
  } while (0)

#define ST_B(buf, tt, h)                                                        \
  do {                                                                          \
    async_load16(pB + (size_t)((h) * 64) * K + (size_t)(tt) * 64,               \
                 &sB[buf][(h) * 4096 + lws]);                                   \
    async_load16(pB + (size_t)((h) * 64 + 128) * K + (size_t)(tt) * 64,         \
                 &sB[buf][(h) * 4096 + 8192 + lws]);                            \
  } while (0)

#define RD_A(dst, sAd, mh)                                                      \
  do {                                                                          \
    _Pragma("unroll") for (int i = 0; i < 4; ++i) {                             \
      const int rb = (wm * 128 + (mh) * 64 + i * 16 + l16) * 64;                \
      dst[i][0] = *(const bf16x8*)&(sAd)[rb + ach0];                            \
      dst[i][1] = *(const bf16x8*)&(sAd)[rb + ach1];                            \
    }                                                                           \
  } while (0)

#define RD_B(dst, sBd, nh)                                                      \
  do {                                                                          \
    _Pragma("unroll") for (int j = 0; j < 2; ++j) {                             \
      const int rb = (wn * 64 + (nh) * 32 + j * 16 + l16) * 64;                 \
      dst[j][0] = *(const bf16x8*)&(sBd)[rb + ach0];                            \
      dst[j][1] = *(const bf16x8*)&(sBd)[rb + ach1];                            \
    }                                                                           \
  } while (0)

#define G_MM(mh, nh, AF, BF)                                                    \
  __builtin_amdgcn_s_setprio(1);                                                \
  _Pragma("unroll") for (int kk = 0; kk < 2; ++kk)                              \
  _Pragma("unroll") for (int i = 0; i < 4; ++i)                                 \
  _Pragma("unroll") for (int j = 0; j < 2; ++j)                                 \
    acc[(mh) * 4 + i][(nh) * 2 + j] =                                           \
        MFMA_16x16x32(AF[i][kk], BF[j][kk], acc[(mh) * 4 + i][(nh) * 2 + j]);   \
  __builtin_amdgcn_s_setprio(0);

__global__ __launch_bounds__(512, 2)
void gemm_bt(const bf16* __restrict__ A, const bf16* __restrict__ B,
             bf16* __restrict__ Cb, float* __restrict__ Cf,
             int M, int N, int K)
{
  __shared__ __align__(16) bf16 sA[2][256 * 64];
  __shared__ __align__(16) bf16 sB[2][256 * 64];

  const int tid  = threadIdx.x;
  const int lane = tid & 63;
  const int w    = tid >> 6;   // 0..7
  const int wm   = w >> 2;     // 0..1
  const int wn   = w & 3;      // 0..3
  const int quad = lane >> 4;
  const int l16  = lane & 15;

  // 1-D grid, bijective XCD swizzle (nwg % 8 == 0 for all our launches)
  const int nbx = N >> 8;
  const int nwg = nbx * (M >> 8);
  const int wg  = (blockIdx.x & 7) * (nwg >> 3) + (blockIdx.x >> 3);
  const int tileM = (wg / nbx) << 8;
  const int tileN = (wg % nbx) << 8;

  // staging: thread writes physical chunk (tid&7) of row srow (+64/128/192);
  // source fetches logical chunk (tid&7)^(srow&7)  (both-sides swizzle).
  const int srow = tid >> 3;                          // 0..63
  const int scol = ((tid & 7) ^ (srow & 7)) << 3;     // pre-swizzled (elems)
  const bf16* pA = A + (size_t)(tileM + srow) * K + scol;
  const bf16* pB = B + (size_t)(tileN + srow) * K + scol;
  const int lws = w * 512;                            // wave lds base in a set

  // ds-read swizzled chunk offsets: logical chunk kk*4+quad, row&7 = l16&7
  const int ach0 = ((quad ^ (l16 & 7)) << 3);
  const int ach1 = (((4 + quad) ^ (l16 & 7)) << 3);

  floatx4 acc[8][4];
#pragma unroll
  for (int i = 0; i < 8; ++i)
#pragma unroll
    for (int j = 0; j < 4; ++j) acc[i][j] = (floatx4){0.f, 0.f, 0.f, 0.f};

  const int T = K >> 6;  // requires T >= 2 (K >= 128)

  bf16x8 af0[4][2], af1[4][2], bf0[2][2], bf1[2][2];

  // ---- prologue: stage tiles 0 and 1 fully; order defines the vmcnt ledger:
  // [A0(0) B0(0) A1(0) B1(0) | A0(1) B0(1) A1(1) B1(1)]  (2 loads each)
  ST_A(0, 0, 0); ST_B(0, 0, 0); ST_A(0, 0, 1); ST_B(0, 0, 1);
  ST_A(1, 1, 0); ST_B(1, 1, 0); ST_A(1, 1, 1); ST_B(1, 1, 1);
  asm volatile("s_waitcnt vmcnt(14)" ::: "memory");  // A0(0) landed
  G_BAR;
  RD_A(af0, (&sA[0][0]), 0);  // af0(tile 0)

  for (int t = 0; t < T; ++t) {
    const int P = t & 1;
    const bf16* sAd = &sA[P][0];
    const bf16* sBd = &sB[P][0];
    const bf16* sAn = &sA[P ^ 1][0];

    // ---- s0: MFMA(0,0) || read bf0,bf1(t); stage A0(t+2)
    if (t + 1 < T) { asm volatile("s_waitcnt vmcnt(8)" ::: "memory"); }
    else           { asm volatile("s_waitcnt vmcnt(0)" ::: "memory"); }
    G_BAR;
    RD_B(bf0, sBd, 0);
    RD_B(bf1, sBd, 1);
    if (t + 2 < T) { ST_A(P, t + 2, 0); }
    G_MM(0, 0, af0, bf0);

    // ---- s1: MFMA(0,1) || read af1(t)
    G_BAR;
    RD_A(af1, sAd, 1);
    G_MM(0, 1, af0, bf1);

    // ---- s2: MFMA(1,1) || read af0(t+1); stage B0(t+2)
    if (t + 2 < T)      { asm volatile("s_waitcnt vmcnt(8)" ::: "memory"); }
    else if (t + 1 < T) { asm volatile("s_waitcnt vmcnt(6)" ::: "memory"); }
    else                { asm volatile("s_waitcnt vmcnt(0)" ::: "memory"); }
    G_BAR;
    if (t + 1 < T) { RD_A(af0, sAn, 0); }
    if (t + 2 < T) { ST_B(P, t + 2, 0); }
    G_MM(1, 1, af1, bf1);

    // ---- s3: MFMA(1,0); stage A1(t+2), B1(t+2)
    G_BAR;
    if (t + 2 < T) { ST_A(P, t + 2, 1); ST_B(P, t + 2, 1); }
    G_MM(1, 0, af1, bf0);
  }

  // ---- epilogue
  const int orow = tileM + wm * 128 + quad * 4;
  const int ocol = tileN + wn * 64 + l16;
  if (Cf) {
#pragma unroll
    for (int fm = 0; fm < 8; ++fm)
#pragma unroll
      for (int fn = 0; fn < 4; ++fn)
#pragma unroll
        for (int r = 0; r < 4; ++r)
          Cf[(size_t)(orow + fm * 16 + r) * N + ocol + fn * 16] = acc[fm][fn][r];
  } else {
#pragma unroll
    for (int fm = 0; fm < 8; ++fm)
#pragma unroll
      for (int fn = 0; fn < 4; ++fn)
#pragma unroll
        for (int r = 0; r < 4; ++r)
          Cb[(size_t)(orow + fm * 16 + r) * N + ocol + fn * 16] =
              __float2bfloat16(acc[fm][fn][r]);
  }
}

// ---------------------------------------------------------------------------
// V transpose: qkv[b*T+t, 4096 + h*128 + dim] -> Vt[(bh*128 + dim)*2048 + t]
// ---------------------------------------------------------------------------
__global__ __launch_bounds__(256)
void transpose_v(const bf16* __restrict__ qkv, bf16* __restrict__ Vt)
{
  __shared__ bf16 tile[64 * 128];
  const int t0 = blockIdx.x * 64;
  const int bh = blockIdx.y;
  const int b = bh >> 4;
  const int h = bh & 15;
  const int tid = threadIdx.x;
  const bf16* src = qkv + (size_t)(b * 2048 + t0) * 6144 + 4096 + h * 128;
#pragma unroll
  for (int s = 0; s < 4; ++s) {
    const int cid = s * 256 + tid;
    const int row = cid >> 4;
    const int col = (cid & 15) << 3;
    *(ushort8*)&tile[row * 128 + col] = *(const ushort8*)&src[(size_t)row * 6144 + col];
  }
  __syncthreads();
  const int dim = tid >> 1;
  const int tp  = (tid & 1) << 5;
  bf16 vals[32];
#pragma unroll
  for (int t = 0; t < 32; ++t) vals[t] = tile[(tp + t) * 128 + dim];
  bf16* dst = Vt + (size_t)(bh * 128 + dim) * 2048 + t0 + tp;
#pragma unroll
  for (int s = 0; s < 4; ++s) *(ushort8*)&dst[s * 8] = ((const ushort8*)vals)[s];
}

// ---------------------------------------------------------------------------
// Flash attention, causal. BQ=128, BKV=32, double-buffered K/V, pipelined.
// 4 waves; wave w owns q-rows w*32..w*32+31 (2 m-subtiles). Q in registers.
// Softmax reductions via DPP (VALU pipe). LDS 42KB -> 3 blocks/CU.
// GRID: x = bh (fast axis, 64), y = q-tile (slow axis, 16, heavy-first).
// ---------------------------------------------------------------------------
__global__ __launch_bounds__(256, 2)
void flash_attn(const bf16* __restrict__ qkv, const bf16* __restrict__ Vt,
                bf16* __restrict__ outb)
{
  // buf p (8192 elems): sK [32 keys][128 d] at +0, sV [128 d][32 keys] at +4096
  // Q (128x128 = 16384 elems) staged once through both bufs. sP after.
  __shared__ __align__(16) bf16 smem[16384 + 4 * 32 * 40];
  bf16* sP = smem + 16384;

  const int qb  = gridDim.y - 1 - blockIdx.y;   // heavy tiles dispatch first
  const int bh  = blockIdx.x;
  const int b   = bh >> 4;
  const int h   = bh & 15;
  const int tid = threadIdx.x;
  const int lane = tid & 63;
  const int w    = tid >> 6;
  const int quad = lane >> 4;
  const int l16  = lane & 15;

  const size_t rs = 6144;
  const bf16* Qg = qkv + (size_t)(b * 2048 + qb * 128) * rs + h * 128;
  const bf16* Kg = qkv + (size_t)(b * 2048) * rs + 2048 + h * 128;
  const bf16* Vg = Vt + (size_t)bh * 128 * 2048;

  // ---- stage Q (128x128), swizzled 16-chunk rows ----
#pragma unroll
  for (int s = 0; s < 8; ++s) {
    const int cid = (w * 8 + s) * 64 + lane;
    const int row = cid >> 4;
    const int col = ((cid & 15) ^ (row & 15)) << 3;
    async_load16(Qg + (size_t)row * rs + col, &smem[(w * 8 + s) * 512]);
  }
  __syncthreads();

  bf16x8 qf[2][4];
#pragma unroll
  for (int i = 0; i < 2; ++i)
#pragma unroll
    for (int kc = 0; kc < 4; ++kc)
      qf[i][kc] = *(const bf16x8*)&smem[(w * 32 + i * 16 + l16) * 128 + (((kc * 4 + quad) ^ l16) << 3)];
  __syncthreads();  // all waves done reading Q before buf0 is overwritten

  // K/V staging index precompute (2 insts each per wave per tile)
  int kq_row[2], kq_col[2], vv_row[2], vv_col[2];
#pragma unroll
  for (int s = 0; s < 2; ++s) {
    const int cid = (w * 2 + s) * 64 + lane;
    kq_row[s] = cid >> 4;                               // 16 chunks per 128-d row
    kq_col[s] = ((cid & 15) ^ (kq_row[s] & 15)) << 3;
    vv_row[s] = cid >> 2;                               // 4 chunks per 32-key row
    vv_col[s] = ((cid & 3) ^ (vv_row[s] & 3)) << 3;
  }

  const int kb_end = 4 * qb + 4;
  // prologue: stage tile 0 into buf 0
#pragma unroll
  for (int s = 0; s < 2; ++s) {
    async_load16(Kg + (size_t)kq_row[s] * rs + kq_col[s],      &smem[(w * 2 + s) * 512]);
    async_load16(Vg + (size_t)vv_row[s] * 2048 + vv_col[s],    &smem[4096 + (w * 2 + s) * 512]);
  }

  floatx4 o[2][8];
#pragma unroll
  for (int i = 0; i < 2; ++i)
#pragma unroll
    for (int s = 0; s < 8; ++s) o[i][s] = (floatx4){0.f, 0.f, 0.f, 0.f};
  float m_i[2][4], l_i[2][4];
#pragma unroll
  for (int i = 0; i < 2; ++i)
#pragma unroll
    for (int r = 0; r < 4; ++r) { m_i[i][r] = -__builtin_inff(); l_i[i][r] = 0.f; }

  const float csc = 1.4426950408889634f * 0.08838834764831845f; // log2(e)/sqrt(128)

  for (int kb = 0; kb < kb_end; ++kb) {
    __syncthreads();  // drains loads(kb) (issued last iter) + protects bufs
    if (kb + 1 < kb_end) {
      bf16* nb = smem + ((kb + 1) & 1) * 8192;
#pragma unroll
      for (int s = 0; s < 2; ++s) {
        async_load16(Kg + (size_t)((kb + 1) * 32 + kq_row[s]) * rs + kq_col[s], nb + (w * 2 + s) * 512);
        async_load16(Vg + (size_t)vv_row[s] * 2048 + (kb + 1) * 32 + vv_col[s], nb + 4096 + (w * 2 + s) * 512);
      }
    }
    // wave-uniform skip: whole key tile above all of this wave's rows
    if (kb * 32 > qb * 128 + w * 32 + 31) continue;

    const bf16* sK = smem + (kb & 1) * 8192;
    const bf16* sV = sK + 4096;

    // S = Q_w(32x128) @ K^T(128x32)
    floatx4 sacc[2][2];
#pragma unroll
    for (int i = 0; i < 2; ++i)
#pragma unroll
      for (int j = 0; j < 2; ++j) sacc[i][j] = (floatx4){0.f, 0.f, 0.f, 0.f};
#pragma unroll
    for (int kc = 0; kc < 4; ++kc) {
      const int ch = ((kc * 4 + quad) ^ l16) << 3;
#pragma unroll
      for (int j = 0; j < 2; ++j) {
        const bf16x8 bk = *(const bf16x8*)&sK[(j * 16 + l16) * 128 + ch];
        sacc[0][j] = MFMA_16x16x32(qf[0][kc], bk, sacc[0][j]);
        sacc[1][j] = MFMA_16x16x32(qf[1][kc], bk, sacc[1][j]);
      }
    }

    // scale + causal mask + online softmax (row = 16 contiguous lanes)
    const bool diag = (kb * 32 + 31 > qb * 128 + w * 32);
    float p[2][2][4];
#pragma unroll
    for (int i = 0; i < 2; ++i) {
      const int qrow = qb * 128 + w * 32 + i * 16 + quad * 4;
#pragma unroll
      for (int r = 0; r < 4; ++r) {
        float mx = -__builtin_inff();
#pragma unroll
        for (int j = 0; j < 2; ++j) {
          float v = sacc[i][j][r] * csc;
          if (diag && kb * 32 + j * 16 + l16 > qrow + r) v = -__builtin_inff();
          p[i][j][r] = v;
          mx = fmaxf(mx, v);
        }
        mx = row_max16(mx);
        const float mnew = fmaxf(m_i[i][r], mx);
        const float alpha = __builtin_amdgcn_exp2f(m_i[i][r] - mnew);
        m_i[i][r] = mnew;
        float rsl = 0.f;
#pragma unroll
        for (int j = 0; j < 2; ++j) {
          const float e = __builtin_amdgcn_exp2f(p[i][j][r] - mnew);
          p[i][j][r] = e;
          rsl += e;
        }
        l_i[i][r] = alpha * l_i[i][r] + row_sum16(rsl);
#pragma unroll
        for (int s = 0; s < 8; ++s) o[i][s][r] *= alpha;
      }
    }

    // P: C-layout regs -> LDS (pad 40, 16B-aligned rows) -> A-layout frags
#pragma unroll
    for (int i = 0; i < 2; ++i)
#pragma unroll
      for (int j = 0; j < 2; ++j)
#pragma unroll
        for (int r = 0; r < 4; ++r)
          sP[w * 1280 + (i * 16 + quad * 4 + r) * 40 + j * 16 + l16] = __float2bfloat16(p[i][j][r]);

    // O += P(32x32) @ V(32x128): single K-step (BKV=32)
    const bf16x8 ap0 = *(const bf16x8*)&sP[w * 1280 + l16 * 40 + quad * 8];
    const bf16x8 ap1 = *(const bf16x8*)&sP[w * 1280 + (16 + l16) * 40 + quad * 8];
    const int chv = (quad ^ (l16 & 3)) << 3;
#pragma unroll
    for (int s = 0; s < 8; ++s) {
      const bf16x8 bv = *(const bf16x8*)&sV[(s * 16 + l16) * 32 + chv];
      o[0][s] = MFMA_16x16x32(ap0, bv, o[0][s]);
      o[1][s] = MFMA_16x16x32(ap1, bv, o[1][s]);
    }
  }

  // epilogue: O /= l, write bf16
#pragma unroll
  for (int i = 0; i < 2; ++i) {
    float rl[4];
#pragma unroll
    for (int r = 0; r < 4; ++r) rl[r] = 1.f / l_i[i][r];
    bf16* dst = outb + (size_t)(b * 2048 + qb * 128 + w * 32 + i * 16) * 2048 + h * 128;
#pragma unroll
    for (int s = 0; s < 8; ++s)
#pragma unroll
      for (int r = 0; r < 4; ++r)
        dst[(size_t)(quad * 4 + r) * 2048 + s * 16 + l16] = __float2bfloat16(o[i][s][r] * rl[r]);
  }
}

// ---------------------------------------------------------------------------
extern "C" void kernel_launch(void* const* d_in, const int* in_sizes, int n_in,
                              void* d_out, int out_size, void* d_ws, size_t ws_size,
                              hipStream_t stream)
{
  (void)in_sizes; (void)n_in; (void)out_size; (void)ws_size;
  const float* x  = (const float*)d_in[0];   // [4,2048,2048]
  const float* Wa = (const float*)d_in[1];   // [6144,2048]
  const float* Wp = (const float*)d_in[2];   // [2048,2048]
  float* out = (float*)d_out;                // [4,2048,2048] fp32
  char* ws = (char*)d_ws;

  bf16* xb   = (bf16*)(ws + 0);              //  33,554,432  x bf16 (dead after GEMM1)
  bf16* Wab  = (bf16*)(ws + 33554432ull);    //  25,165,824  W_attn bf16
  bf16* Wpb  = (bf16*)(ws + 58720256ull);    //   8,388,608  W_proj bf16
  bf16* qkv  = (bf16*)(ws + 67108864ull);    // 100,663,296  [8192,6144] bf16
  bf16* attb = (bf16*)(ws + 167772160ull);   //  33,554,432  attn out bf16
  bf16* Vt   = xb;                           // alias: V transposed [64][128][2048]

  f32_to_bf16_k<<<8192, 256, 0, stream>>>(x,  xb,  4 * 2048 * 2048);
  f32_to_bf16_k<<<6144, 256, 0, stream>>>(Wa, Wab, 3 * 2048 * 2048);
  f32_to_bf16_k<<<2048, 256, 0, stream>>>(Wp, Wpb, 2048 * 2048);

  // qkv = x @ W_attn^T   [8192,6144]; 256x256 tiles -> 24x32 = 768 wgs
  gemm_bt<<<dim3(768), 512, 0, stream>>>(xb, Wab, qkv, nullptr, 8192, 6144, 2048);
  // Vt[bh][d][t]
  transpose_v<<<dim3(32, 64), 256, 0, stream>>>(qkv, Vt);
  // attention: x = bh (64), y = q-tile (16, heavy-first) for per-CU balance
  flash_attn<<<dim3(64, 16), 256, 0, stream>>>(qkv, Vt, attb);
  // out = attb @ W_proj^T  [8192,2048] fp32; 8x32 = 256 wgs
  gemm_bt<<<dim3(256), 512, 0, stream>>>(attb, Wpb, nullptr, out, 8192, 2048, 2048);
}

// Round 5
// 583.665 us; speedup vs baseline: 1.0444x; 1.0444x over previous
//
#include <hip/hip_runtime.h>
#include <hip/hip_bf16.h>
#include <stdint.h>

typedef __hip_bfloat16 bf16;
typedef __attribute__((ext_vector_type(8))) __bf16 bf16x8;
typedef __attribute__((ext_vector_type(8))) unsigned short ushort8;
typedef __attribute__((ext_vector_type(4))) float floatx4;

#define MFMA_16x16x32(a, b, c) __builtin_amdgcn_mfma_f32_16x16x32_bf16((a), (b), (c), 0, 0, 0)

// async global->LDS, 16B per lane. LDS dest = wave-uniform base + lane*16.
__device__ __forceinline__ void async_load16(const bf16* g, bf16* l) {
  __builtin_amdgcn_global_load_lds(
      (const __attribute__((address_space(1))) unsigned int*)g,
      (__attribute__((address_space(3))) unsigned int*)l,
      16, 0, 0);
}

// DPP cross-lane (VALU pipe, not LDS): 16-lane row reductions
template <int CTRL>
__device__ __forceinline__ float dpp_f(float x) {
  return __builtin_bit_cast(float, __builtin_amdgcn_update_dpp(
      0, __builtin_bit_cast(int, x), CTRL, 0xf, 0xf, true));
}
__device__ __forceinline__ float row_max16(float x) {
  x = fmaxf(x, dpp_f<0xB1>(x));   // quad_perm(1,0,3,2)
  x = fmaxf(x, dpp_f<0x4E>(x));   // quad_perm(2,3,0,1)
  x = fmaxf(x, dpp_f<0x124>(x));  // row_ror:4
  x = fmaxf(x, dpp_f<0x128>(x));  // row_ror:8
  return x;
}
__device__ __forceinline__ float row_sum16(float x) {
  x += dpp_f<0xB1>(x);
  x += dpp_f<0x4E>(x);
  x += dpp_f<0x124>(x);
  x += dpp_f<0x128>(x);
  return x;
}

// ---------------------------------------------------------------------------
// fp32 -> bf16 cast, 8 elems/thread
// ---------------------------------------------------------------------------
__global__ __launch_bounds__(256)
void f32_to_bf16_k(const float* __restrict__ in, bf16* __restrict__ out, int n)
{
  const int i = (blockIdx.x * 256 + threadIdx.x) * 8;
  if (i >= n) return;
  bf16 tmp[8];
#pragma unroll
  for (int j = 0; j < 8; ++j) tmp[j] = __float2bfloat16(in[i + j]);
  *(ushort8*)&out[i] = *(const ushort8*)tmp;
}

// ---------------------------------------------------------------------------
// C[M,N] = A[M,K] @ B[N,K]^T — 256x256 tile, BK=64, 8-phase (R3 structure:
// reads in-phase, {reads|stage|BAR|MFMA|BAR}).  R5 deltas vs R3:
//  (1) template<K> + 2x-unrolled K-loop: LDS buffer parity is compile-time,
//      so every ds_read folds to base+offset: immediate (VALU ~0 in loop).
//  (2) deepened vmcnt: two counted waits per tile.
// Load ledger (steady, 2 loads per STG; issue order within tile t:
//   P1:SB1(t+1) P2:SA1(t+1) P3:SA0(t+2) P4:SB0(t+2)):
//   entering t: outstanding 6 = [SA1(t), SA0(t+1), SB0(t+1)] (x2 loads each)
//   P2 wait vmcnt(8): 10 outstanding -> drains SA1(t)  (4-phase slack; P3 reads A1(t))
//   P4 wait vmcnt(6): 12 outstanding -> drains SA0(t+1),SB0(t+1),SB1(t+1)
//      (5-6 / 3-phase slack; t+1.P1 reads A0,B0; t+1.P2 reads B1)
// Tails: t=T-2 -> P4 vmcnt(2); t=T-1 -> P2/P4 vmcnt(0). Prologue order
//   [A0(0) B0(0) B1(0) A1(0) A0(1) B0(1)] + vmcnt(6) reproduces steady state.
// ---------------------------------------------------------------------------
#define G_BAR __builtin_amdgcn_s_barrier()
#define WAITV(n) asm volatile("s_waitcnt vmcnt(" #n ")" ::: "memory")

#define STG(P_, dstArr, pg, tt, h)                                              \
  do {                                                                          \
    async_load16((pg) + (size_t)((h) * 64) * K + (size_t)(tt) * 64,             \
                 &dstArr[P_][(h) * 4096 + lws]);                                \
    async_load16((pg) + (size_t)((h) * 64 + 128) * K + (size_t)(tt) * 64,       \
                 &dstArr[P_][(h) * 4096 + 8192 + lws]);                         \
  } while (0)

#define RD_A(P_, mh)                                                            \
  do {                                                                          \
    _Pragma("unroll") for (int i = 0; i < 4; ++i) {                             \
      const int rb = (wm * 128 + (mh) * 64 + i * 16 + l16) * 64;                \
      af[i][0] = *(const bf16x8*)&sA[P_][rb + ach0];                            \
      af[i][1] = *(const bf16x8*)&sA[P_][rb + ach1];                            \
    }                                                                           \
  } while (0)

#define RD_B(P_, dst, nh)                                                       \
  do {                                                                          \
    _Pragma("unroll") for (int j = 0; j < 2; ++j) {                             \
      const int rb = (wn * 64 + (nh) * 32 + j * 16 + l16) * 64;                 \
      dst[j][0] = *(const bf16x8*)&sB[P_][rb + ach0];                           \
      dst[j][1] = *(const bf16x8*)&sB[P_][rb + ach1];                           \
    }                                                                           \
  } while (0)

#define G_MM(mh, nh, BF)                                                        \
  __builtin_amdgcn_s_setprio(1);                                                \
  _Pragma("unroll") for (int kk = 0; kk < 2; ++kk)                              \
  _Pragma("unroll") for (int i = 0; i < 4; ++i)                                 \
  _Pragma("unroll") for (int j = 0; j < 2; ++j)                                 \
    acc[(mh) * 4 + i][(nh) * 2 + j] =                                           \
        MFMA_16x16x32(af[i][kk], BF[j][kk], acc[(mh) * 4 + i][(nh) * 2 + j]);   \
  __builtin_amdgcn_s_setprio(0);

#define TILE_ITER(t_, P_)                                                       \
  {                                                                             \
    /* P1: quadrant (0,0) */                                                    \
    RD_A(P_, 0);                                                                \
    RD_B(P_, bf0, 0);                                                           \
    if ((t_) + 1 < T) STG((P_) ^ 1, sB, pB, (t_) + 1, 1);                       \
    G_BAR; G_MM(0, 0, bf0); G_BAR;                                              \
    /* P2: quadrant (0,1) */                                                    \
    RD_B(P_, bf1, 1);                                                           \
    if ((t_) + 1 < T) STG((P_) ^ 1, sA, pA, (t_) + 1, 1);                       \
    G_BAR; G_MM(0, 1, bf1);                                                     \
    if ((t_) + 1 < T) { WAITV(8); } else { WAITV(0); }                          \
    G_BAR;                                                                      \
    /* P3: quadrant (1,0) */                                                    \
    RD_A(P_, 1);                                                                \
    if ((t_) + 2 < T) STG(P_, sA, pA, (t_) + 2, 0);                             \
    G_BAR; G_MM(1, 0, bf0); G_BAR;                                              \
    /* P4: quadrant (1,1) */                                                    \
    if ((t_) + 2 < T) STG(P_, sB, pB, (t_) + 2, 0);                             \
    G_BAR; G_MM(1, 1, bf1);                                                     \
    if ((t_) + 2 < T)      { WAITV(6); }                                        \
    else if ((t_) + 1 < T) { WAITV(2); }                                        \
    else                   { WAITV(0); }                                        \
    G_BAR;                                                                      \
  }

template <int K>
__global__ __launch_bounds__(512, 2)
void gemm_bt(const bf16* __restrict__ A, const bf16* __restrict__ B,
             bf16* __restrict__ Cb, float* __restrict__ Cf,
             int M, int N)
{
  __shared__ __align__(16) bf16 sA[2][256 * 64];
  __shared__ __align__(16) bf16 sB[2][256 * 64];

  const int tid  = threadIdx.x;
  const int lane = tid & 63;
  const int w    = tid >> 6;   // 0..7
  const int wm   = w >> 2;     // 0..1
  const int wn   = w & 3;      // 0..3
  const int quad = lane >> 4;
  const int l16  = lane & 15;

  // 1-D grid, bijective XCD swizzle (nwg % 8 == 0 for all our launches)
  const int nbx = N >> 8;
  const int nwg = nbx * (M >> 8);
  const int wg  = (blockIdx.x & 7) * (nwg >> 3) + (blockIdx.x >> 3);
  const int tileM = (wg / nbx) << 8;
  const int tileN = (wg % nbx) << 8;

  // staging: thread writes physical chunk (tid&7) of row srow (+64/128/192);
  // source fetches logical chunk (tid&7)^(srow&7)  (both-sides swizzle).
  const int srow = tid >> 3;                          // 0..63
  const int scol = ((tid & 7) ^ (srow & 7)) << 3;     // pre-swizzled (elems)
  const bf16* pA = A + (size_t)(tileM + srow) * K + scol;
  const bf16* pB = B + (size_t)(tileN + srow) * K + scol;
  const int lws = w * 512;                            // wave lds base in a set

  // ds-read swizzled chunk offsets: logical chunk kk*4+quad, row&7 = l16&7
  const int ach0 = ((quad ^ (l16 & 7)) << 3);
  const int ach1 = (((4 + quad) ^ (l16 & 7)) << 3);

  floatx4 acc[8][4];
#pragma unroll
  for (int i = 0; i < 8; ++i)
#pragma unroll
    for (int j = 0; j < 4; ++j) acc[i][j] = (floatx4){0.f, 0.f, 0.f, 0.f};

  const int T = K >> 6;  // even, >= 2 for all our shapes (K=2048 -> T=32)

  bf16x8 af[4][2], bf0[2][2], bf1[2][2];

  // ---- prologue: issue order [A0(0) B0(0) B1(0) A1(0) | A0(1) B0(1)]
  STG(0, sA, pA, 0, 0);
  STG(0, sB, pB, 0, 0);
  STG(0, sB, pB, 0, 1);
  STG(0, sA, pA, 0, 1);
  if (T > 1) {
    STG(1, sA, pA, 1, 0);
    STG(1, sB, pB, 1, 0);
    WAITV(6);   // drains A0(0),B0(0),B1(0); leaves [A1(0),A0(1),B0(1)]
  } else {
    WAITV(0);
  }
  G_BAR;

  for (int t = 0; t < T; t += 2) {
    TILE_ITER(t, 0);
    TILE_ITER(t + 1, 1);
  }

  // ---- epilogue
  const int orow = tileM + wm * 128 + quad * 4;
  const int ocol = tileN + wn * 64 + l16;
  if (Cf) {
#pragma unroll
    for (int fm = 0; fm < 8; ++fm)
#pragma unroll
      for (int fn = 0; fn < 4; ++fn)
#pragma unroll
        for (int r = 0; r < 4; ++r)
          Cf[(size_t)(orow + fm * 16 + r) * N + ocol + fn * 16] = acc[fm][fn][r];
  } else {
#pragma unroll
    for (int fm = 0; fm < 8; ++fm)
#pragma unroll
      for (int fn = 0; fn < 4; ++fn)
#pragma unroll
        for (int r = 0; r < 4; ++r)
          Cb[(size_t)(orow + fm * 16 + r) * N + ocol + fn * 16] =
              __float2bfloat16(acc[fm][fn][r]);
  }
}

// ---------------------------------------------------------------------------
// V transpose: qkv[b*T+t, 4096 + h*128 + dim] -> Vt[(bh*128 + dim)*2048 + t]
// ---------------------------------------------------------------------------
__global__ __launch_bounds__(256)
void transpose_v(const bf16* __restrict__ qkv, bf16* __restrict__ Vt)
{
  __shared__ bf16 tile[64 * 128];
  const int t0 = blockIdx.x * 64;
  const int bh = blockIdx.y;
  const int b = bh >> 4;
  const int h = bh & 15;
  const int tid = threadIdx.x;
  const bf16* src = qkv + (size_t)(b * 2048 + t0) * 6144 + 4096 + h * 128;
#pragma unroll
  for (int s = 0; s < 4; ++s) {
    const int cid = s * 256 + tid;
    const int row = cid >> 4;
    const int col = (cid & 15) << 3;
    *(ushort8*)&tile[row * 128 + col] = *(const ushort8*)&src[(size_t)row * 6144 + col];
  }
  __syncthreads();
  const int dim = tid >> 1;
  const int tp  = (tid & 1) << 5;
  bf16 vals[32];
#pragma unroll
  for (int t = 0; t < 32; ++t) vals[t] = tile[(tp + t) * 128 + dim];
  bf16* dst = Vt + (size_t)(bh * 128 + dim) * 2048 + t0 + tp;
#pragma unroll
  for (int s = 0; s < 4; ++s) *(ushort8*)&dst[s * 8] = ((const ushort8*)vals)[s];
}

// ---------------------------------------------------------------------------
// Flash attention, causal. BQ=128, BKV=32, double-buffered K/V, pipelined.
// 4 waves; wave w owns q-rows w*32..w*32+31 (2 m-subtiles). Q in registers.
// Softmax reductions via DPP (VALU pipe). LDS 42KB -> 3 blocks/CU.
// GRID: x = bh (fast axis, 64), y = q-tile (slow axis, 16, heavy-first).
// ---------------------------------------------------------------------------
__global__ __launch_bounds__(256, 2)
void flash_attn(const bf16* __restrict__ qkv, const bf16* __restrict__ Vt,
                bf16* __restrict__ outb)
{
  // buf p (8192 elems): sK [32 keys][128 d] at +0, sV [128 d][32 keys] at +4096
  // Q (128x128 = 16384 elems) staged once through both bufs. sP after.
  __shared__ __align__(16) bf16 smem[16384 + 4 * 32 * 40];
  bf16* sP = smem + 16384;

  const int qb  = gridDim.y - 1 - blockIdx.y;   // heavy tiles dispatch first
  const int bh  = blockIdx.x;
  const int b   = bh >> 4;
  const int h   = bh & 15;
  const int tid = threadIdx.x;
  const int lane = tid & 63;
  const int w    = tid >> 6;
  const int quad = lane >> 4;
  const int l16  = lane & 15;

  const size_t rs = 6144;
  const bf16* Qg = qkv + (size_t)(b * 2048 + qb * 128) * rs + h * 128;
  const bf16* Kg = qkv + (size_t)(b * 2048) * rs + 2048 + h * 128;
  const bf16* Vg = Vt + (size_t)bh * 128 * 2048;

  // ---- stage Q (128x128), swizzled 16-chunk rows ----
#pragma unroll
  for (int s = 0; s < 8; ++s) {
    const int cid = (w * 8 + s) * 64 + lane;
    const int row = cid >> 4;
    const int col = ((cid & 15) ^ (row & 15)) << 3;
    async_load16(Qg + (size_t)row * rs + col, &smem[(w * 8 + s) * 512]);
  }
  __syncthreads();

  bf16x8 qf[2][4];
#pragma unroll
  for (int i = 0; i < 2; ++i)
#pragma unroll
    for (int kc = 0; kc < 4; ++kc)
      qf[i][kc] = *(const bf16x8*)&smem[(w * 32 + i * 16 + l16) * 128 + (((kc * 4 + quad) ^ l16) << 3)];
  __syncthreads();  // all waves done reading Q before buf0 is overwritten

  // K/V staging index precompute (2 insts each per wave per tile)
  int kq_row[2], kq_col[2], vv_row[2], vv_col[2];
#pragma unroll
  for (int s = 0; s < 2; ++s) {
    const int cid = (w * 2 + s) * 64 + lane;
    kq_row[s] = cid >> 4;                               // 16 chunks per 128-d row
    kq_col[s] = ((cid & 15) ^ (kq_row[s] & 15)) << 3;
    vv_row[s] = cid >> 2;                               // 4 chunks per 32-key row
    vv_col[s] = ((cid & 3) ^ (vv_row[s] & 3)) << 3;
  }

  const int kb_end = 4 * qb + 4;
  // prologue: stage tile 0 into buf 0
#pragma unroll
  for (int s = 0; s < 2; ++s) {
    async_load16(Kg + (size_t)kq_row[s] * rs + kq_col[s],      &smem[(w * 2 + s) * 512]);
    async_load16(Vg + (size_t)vv_row[s] * 2048 + vv_col[s],    &smem[4096 + (w * 2 + s) * 512]);
  }

  floatx4 o[2][8];
#pragma unroll
  for (int i = 0; i < 2; ++i)
#pragma unroll
    for (int s = 0; s < 8; ++s) o[i][s] = (floatx4){0.f, 0.f, 0.f, 0.f};
  float m_i[2][4], l_i[2][4];
#pragma unroll
  for (int i = 0; i < 2; ++i)
#pragma unroll
    for (int r = 0; r < 4; ++r) { m_i[i][r] = -__builtin_inff(); l_i[i][r] = 0.f; }

  const float csc = 1.4426950408889634f * 0.08838834764831845f; // log2(e)/sqrt(128)

  for (int kb = 0; kb < kb_end; ++kb) {
    __syncthreads();  // drains loads(kb) (issued last iter) + protects bufs
    if (kb + 1 < kb_end) {
      bf16* nb = smem + ((kb + 1) & 1) * 8192;
#pragma unroll
      for (int s = 0; s < 2; ++s) {
        async_load16(Kg + (size_t)((kb + 1) * 32 + kq_row[s]) * rs + kq_col[s], nb + (w * 2 + s) * 512);
        async_load16(Vg + (size_t)vv_row[s] * 2048 + (kb + 1) * 32 + vv_col[s], nb + 4096 + (w * 2 + s) * 512);
      }
    }
    // wave-uniform skip: whole key tile above all of this wave's rows
    if (kb * 32 > qb * 128 + w * 32 + 31) continue;

    const bf16* sK = smem + (kb & 1) * 8192;
    const bf16* sV = sK + 4096;

    // S = Q_w(32x128) @ K^T(128x32)
    floatx4 sacc[2][2];
#pragma unroll
    for (int i = 0; i < 2; ++i)
#pragma unroll
      for (int j = 0; j < 2; ++j) sacc[i][j] = (floatx4){0.f, 0.f, 0.f, 0.f};
#pragma unroll
    for (int kc = 0; kc < 4; ++kc) {
      const int ch = ((kc * 4 + quad) ^ l16) << 3;
#pragma unroll
      for (int j = 0; j < 2; ++j) {
        const bf16x8 bk = *(const bf16x8*)&sK[(j * 16 + l16) * 128 + ch];
        sacc[0][j] = MFMA_16x16x32(qf[0][kc], bk, sacc[0][j]);
        sacc[1][j] = MFMA_16x16x32(qf[1][kc], bk, sacc[1][j]);
      }
    }

    // scale + causal mask + online softmax (row = 16 contiguous lanes)
    const bool diag = (kb * 32 + 31 > qb * 128 + w * 32);
    float p[2][2][4];
#pragma unroll
    for (int i = 0; i < 2; ++i) {
      const int qrow = qb * 128 + w * 32 + i * 16 + quad * 4;
#pragma unroll
      for (int r = 0; r < 4; ++r) {
        float mx = -__builtin_inff();
#pragma unroll
        for (int j = 0; j < 2; ++j) {
          float v = sacc[i][j][r] * csc;
          if (diag && kb * 32 + j * 16 + l16 > qrow + r) v = -__builtin_inff();
          p[i][j][r] = v;
          mx = fmaxf(mx, v);
        }
        mx = row_max16(mx);
        const float mnew = fmaxf(m_i[i][r], mx);
        const float alpha = __builtin_amdgcn_exp2f(m_i[i][r] - mnew);
        m_i[i][r] = mnew;
        float rsl = 0.f;
#pragma unroll
        for (int j = 0; j < 2; ++j) {
          const float e = __builtin_amdgcn_exp2f(p[i][j][r] - mnew);
          p[i][j][r] = e;
          rsl += e;
        }
        l_i[i][r] = alpha * l_i[i][r] + row_sum16(rsl);
#pragma unroll
        for (int s = 0; s < 8; ++s) o[i][s][r] *= alpha;
      }
    }

    // P: C-layout regs -> LDS (pad 40, 16B-aligned rows) -> A-layout frags
#pragma unroll
    for (int i = 0; i < 2; ++i)
#pragma unroll
      for (int j = 0; j < 2; ++j)
#pragma unroll
        for (int r = 0; r < 4; ++r)
          sP[w * 1280 + (i * 16 + quad * 4 + r) * 40 + j * 16 + l16] = __float2bfloat16(p[i][j][r]);

    // O += P(32x32) @ V(32x128): single K-step (BKV=32)
    const bf16x8 ap0 = *(const bf16x8*)&sP[w * 1280 + l16 * 40 + quad * 8];
    const bf16x8 ap1 = *(const bf16x8*)&sP[w * 1280 + (16 + l16) * 40 + quad * 8];
    const int chv = (quad ^ (l16 & 3)) << 3;
#pragma unroll
    for (int s = 0; s < 8; ++s) {
      const bf16x8 bv = *(const bf16x8*)&sV[(s * 16 + l16) * 32 + chv];
      o[0][s] = MFMA_16x16x32(ap0, bv, o[0][s]);
      o[1][s] = MFMA_16x16x32(ap1, bv, o[1][s]);
    }
  }

  // epilogue: O /= l, write bf16
#pragma unroll
  for (int i = 0; i < 2; ++i) {
    float rl[4];
#pragma unroll
    for (int r = 0; r < 4; ++r) rl[r] = 1.f / l_i[i][r];
    bf16* dst = outb + (size_t)(b * 2048 + qb * 128 + w * 32 + i * 16) * 2048 + h * 128;
#pragma unroll
    for (int s = 0; s < 8; ++s)
#pragma unroll
      for (int r = 0; r < 4; ++r)
        dst[(size_t)(quad * 4 + r) * 2048 + s * 16 + l16] = __float2bfloat16(o[i][s][r] * rl[r]);
  }
}

// ---------------------------------------------------------------------------
extern "C" void kernel_launch(void* const* d_in, const int* in_sizes, int n_in,
                              void* d_out, int out_size, void* d_ws, size_t ws_size,
                              hipStream_t stream)
{
  (void)in_sizes; (void)n_in; (void)out_size; (void)ws_size;
  const float* x  = (const float*)d_in[0];   // [4,2048,2048]
  const float* Wa = (const float*)d_in[1];   // [6144,2048]
  const float* Wp = (const float*)d_in[2];   // [2048,2048]
  float* out = (float*)d_out;                // [4,2048,2048] fp32
  char* ws = (char*)d_ws;

  bf16* xb   = (bf16*)(ws + 0);              //  33,554,432  x bf16 (dead after GEMM1)
  bf16* Wab  = (bf16*)(ws + 33554432ull);    //  25,165,824  W_attn bf16
  bf16* Wpb  = (bf16*)(ws + 58720256ull);    //   8,388,608  W_proj bf16
  bf16* qkv  = (bf16*)(ws + 67108864ull);    // 100,663,296  [8192,6144] bf16
  bf16* attb = (bf16*)(ws + 167772160ull);   //  33,554,432  attn out bf16
  bf16* Vt   = xb;                           // alias: V transposed [64][128][2048]

  f32_to_bf16_k<<<8192, 256, 0, stream>>>(x,  xb,  4 * 2048 * 2048);
  f32_to_bf16_k<<<6144, 256, 0, stream>>>(Wa, Wab, 3 * 2048 * 2048);
  f32_to_bf16_k<<<2048, 256, 0, stream>>>(Wp, Wpb, 2048 * 2048);

  // qkv = x @ W_attn^T   [8192,6144]; 256x256 tiles -> 24x32 = 768 wgs
  gemm_bt<2048><<<dim3(768), 512, 0, stream>>>(xb, Wab, qkv, nullptr, 8192, 6144);
  // Vt[bh][d][t]
  transpose_v<<<dim3(32, 64), 256, 0, stream>>>(qkv, Vt);
  // attention: x = bh (64), y = q-tile (16, heavy-first) for per-CU balance
  flash_attn<<<dim3(64, 16), 256, 0, stream>>>(qkv, Vt, attb);
  // out = attb @ W_proj^T  [8192,2048] fp32; 8x32 = 256 wgs
  gemm_bt<2048><<<dim3(256), 512, 0, stream>>>(attb, Wpb, nullptr, out, 8192, 2048);
}